// Round 4
// baseline (73.248 us; speedup 1.0000x reference)
//
#include <hip/hip_runtime.h>
#include <hip/hip_bf16.h>
#include <stdint.h>

typedef __attribute__((ext_vector_type(8))) short bf16x8;
typedef __attribute__((ext_vector_type(4))) float f32x4;

#define MFMA16(a, b, c) __builtin_amdgcn_mfma_f32_16x16x32_bf16((a), (b), (c), 0, 0, 0)

__device__ __forceinline__ unsigned short f2bf_rn(float f) {
    union { __bf16 b; unsigned short u; } v;
    v.b = (__bf16)f;                 // RNE; pairs fuse to v_cvt_pk_bf16_f32
    return v.u;
}

__device__ __forceinline__ ushort4 cvt4(f32x4 v) {
    ushort4 r;
    r.x = f2bf_rn(v[0]); r.y = f2bf_rn(v[1]);
    r.z = f2bf_rn(v[2]); r.w = f2bf_rn(v[3]);
    return r;
}

__device__ __forceinline__ void gload_lds16(const void* g, void* l) {
    __builtin_amdgcn_global_load_lds(
        (const __attribute__((address_space(1))) void*)g,
        (__attribute__((address_space(3))) void*)l, 16, 0, 0);
}

// ---------------------------------------------------------------------------
// prep_h: transpose each 128x128 fp32 block of the 8 H tensors to bf16.
//   ht[j][blk][k][r] = h_j[blk][r][k]
// Lt_c = ht[c], Wt_c = ht[rperm[c]] — same transposed data serves both roles.
// ---------------------------------------------------------------------------
__global__ __launch_bounds__(256) void prep_h(
    const float* __restrict__ h0, const float* __restrict__ h1,
    const float* __restrict__ h2, const float* __restrict__ h3,
    const float* __restrict__ h4, const float* __restrict__ h5,
    const float* __restrict__ h6, const float* __restrict__ h7,
    unsigned short* __restrict__ ht)
{
    const float* hmap[8] = {h0, h1, h2, h3, h4, h5, h6, h7};
    const int wg = blockIdx.x;        // 64 = j(8) x blk(8)
    const float* src = hmap[wg >> 3] + (wg & 7) * 16384;
    unsigned short* dst = ht + wg * 16384;
    __shared__ unsigned short tile[128 * 129];
    const int t = threadIdx.x;
    #pragma unroll 4
    for (int i = 0; i < 64; ++i) {
        int idx = t + 256 * i, r = idx >> 7, k = idx & 127;
        tile[r * 129 + k] = f2bf_rn(src[idx]);
    }
    __syncthreads();
    #pragma unroll 4
    for (int i = 0; i < 64; ++i) {
        int idx = t + 256 * i, k = idx >> 7, r = idx & 127;
        dst[idx] = tile[r * 129 + k];
    }
}

// ---------------------------------------------------------------------------
// bilin_main: 256 WGs = (b,p,q), q = bid&7 (XCD-locked: Wt[*][q] + Lt[*][p]
// stay hot in that XCD's 4MB L2). 512 threads = 8 waves in 2(wm)x4(wn),
// wave tile 64x32 of the 128x128 output block. Per c-term:
//   [barrier] issue Lt_c / Wt_{c+1} gload_lds stages -> stage A (xf in REGs,
//   wf from LDS) -> cvt U -> swizzled Ut write -> [barrier: drains gloads]
//   -> stage B (lf, uf from LDS) -> loop.
// X is read directly from the fp32 input with the permutation applied in the
// address (prep_x fused away); identical numerics to staging via bf16 planes.
// LDS data is XOR-swizzled at 16B-chunk granularity: LDS[row][ch] holds
// G[row][ch ^ (row&7)] — reads at b128 are bank-conflict-free.
// ---------------------------------------------------------------------------
__global__ __launch_bounds__(512, 2) void bilin_main(
    const float* __restrict__ x, const int* __restrict__ perm,
    const unsigned short* __restrict__ ht, float* __restrict__ out)
{
    const int wg = blockIdx.x;
    const int q = wg & 7, p = (wg >> 3) & 7, b = wg >> 6;
    const int tid = threadIdx.x;
    const int lane = tid & 63, wid = tid >> 6;
    const int wm = wid >> 2, wn = wid & 3;
    const int lr = lane & 15, lg = lane >> 4;
    const int swz = lr & 7;

    __shared__ __align__(16) unsigned short wlds[2][16384];  // Wt dbuf (2x32KB)
    __shared__ __align__(16) unsigned short llds[16384];     // Lt (32KB)
    __shared__ __align__(16) unsigned short utlds[16384];    // U^T (32KB)

    const int n1  = perm[2 * p + wm];      // this wave's source row block
    const int n2a = perm[2 * q];           // source col blocks
    const int n2b = perm[2 * q + 1];

    constexpr int cseq[8]  = {0, 1, 6, 7, 2, 3, 4, 5};   // c per cc (g = cc>>2)
    constexpr int rperm[8] = {0, 1, 3, 2, 4, 5, 7, 6};   // Wt tensor index per c

    f32x4 yre[4][2], yim[4][2];
    #pragma unroll
    for (int i = 0; i < 4; ++i)
        #pragma unroll
        for (int j = 0; j < 2; ++j) {
            yre[i][j] = (f32x4){0.f, 0.f, 0.f, 0.f};
            yim[i][j] = (f32x4){0.f, 0.f, 0.f, 0.f};
        }

    const int schunk = tid & ~63;          // wave-uniform chunk base

    // stage one 32KB ht block into LDS, source pre-swizzled so a linear
    // gload_lds dest yields LDS[row][ch] = G[row][ch ^ (row&7)]
    auto stage_h = [&](unsigned short* dst, int blk) {
        const unsigned short* src = ht + blk * 16384;
        #pragma unroll
        for (int r = 0; r < 4; ++r) {
            const int idx = r * 512 + tid;        // 16B chunk id 0..2047
            const int row = idx >> 4, cin = idx & 15;
            gload_lds16(src + row * 128 + ((cin ^ (row & 7)) << 3),
                        dst + ((r * 512 + schunk) << 3));
        }
    };

    // load this wave's X fragments (64 rows x 128 K) straight from fp32 input
    auto load_xf = [&](bf16x8 (&xf)[4][4], int g) {
        #pragma unroll
        for (int mt = 0; mt < 4; ++mt) {
            const int r1 = mt * 16 + lr;
            const float* rb = x + (size_t)((b * 16 + n1) * 64 + r1) * 2048;
            #pragma unroll
            for (int ks = 0; ks < 4; ++ks) {
                const int n2 = (ks < 2) ? n2a : n2b;
                const int r2 = (ks & 1) * 32 + lg * 8;
                const float4* sp = (const float4*)(rb + (n2 * 64 + r2) * 2);
                float4 v0 = sp[0], v1 = sp[1], v2 = sp[2], v3 = sp[3];
                bf16x8 t;
                if (g == 0) {
                    t[0] = (short)f2bf_rn(v0.x); t[1] = (short)f2bf_rn(v0.z);
                    t[2] = (short)f2bf_rn(v1.x); t[3] = (short)f2bf_rn(v1.z);
                    t[4] = (short)f2bf_rn(v2.x); t[5] = (short)f2bf_rn(v2.z);
                    t[6] = (short)f2bf_rn(v3.x); t[7] = (short)f2bf_rn(v3.z);
                } else {
                    t[0] = (short)f2bf_rn(v0.y); t[1] = (short)f2bf_rn(v0.w);
                    t[2] = (short)f2bf_rn(v1.y); t[3] = (short)f2bf_rn(v1.w);
                    t[4] = (short)f2bf_rn(v2.y); t[5] = (short)f2bf_rn(v2.w);
                    t[6] = (short)f2bf_rn(v3.y); t[7] = (short)f2bf_rn(v3.w);
                }
                xf[mt][ks] = t;
            }
        }
    };

    // ---- prologue: stage Wt(c0), Lt(c0); load X(g=0)
    bf16x8 xf[4][4];
    stage_h(wlds[0], rperm[0] * 8 + q);
    stage_h(llds, 0 * 8 + p);
    load_xf(xf, 0);
    __syncthreads();

    #pragma unroll
    for (int cc = 0; cc < 8; ++cc) {
        const int c = cseq[cc];

        // issue async stages for this c's Lt and next c's Wt (drain @ barrier)
        if (cc > 0) stage_h(llds, c * 8 + p);
        if (cc < 7) stage_h(wlds[(cc + 1) & 1], rperm[cseq[cc + 1]] * 8 + q);

        // ---- stage A: U = X . W_c   (xf regs, wf LDS)
        const unsigned short* wb = wlds[cc & 1];
        bf16x8 wf[2][4];
        #pragma unroll
        for (int nt = 0; nt < 2; ++nt) {
            const int row = wn * 32 + nt * 16 + lr;
            #pragma unroll
            for (int ks = 0; ks < 4; ++ks)
                wf[nt][ks] = *(const bf16x8*)(wb + row * 128
                                              + (((ks * 4 + lg) ^ swz) << 3));
        }
        f32x4 u[4][2];
        #pragma unroll
        for (int mt = 0; mt < 4; ++mt)
            #pragma unroll
            for (int nt = 0; nt < 2; ++nt)
                u[mt][nt] = (f32x4){0.f, 0.f, 0.f, 0.f};
        #pragma unroll
        for (int ks = 0; ks < 4; ++ks)
            #pragma unroll
            for (int mt = 0; mt < 4; ++mt)
                #pragma unroll
                for (int nt = 0; nt < 2; ++nt)
                    u[mt][nt] = MFMA16(xf[mt][ks], wf[nt][ks], u[mt][nt]);

        // reload X plane for g=1 while cvt/barrier/stageB hide the latency
        if (cc == 3) load_xf(xf, 1);

        // ---- cvt + swizzled U^T write: Ut[ucol][urow]
        #pragma unroll
        for (int nt = 0; nt < 2; ++nt) {
            const int row = wn * 32 + nt * 16 + lr;
            #pragma unroll
            for (int mt = 0; mt < 4; ++mt) {
                const int col = wm * 64 + mt * 16 + lg * 4;
                *(ushort4*)(utlds + row * 128 + (col ^ (swz << 3))) =
                    cvt4(u[mt][nt]);
            }
        }
        __syncthreads();   // orders Ut; drains Lt(c)/Wt(c+1) gloads

        // ---- stage B: Y += Lt_c . U   (lf, uf from LDS)
        bf16x8 uf[2][4];
        #pragma unroll
        for (int nt = 0; nt < 2; ++nt) {
            const int row = wn * 32 + nt * 16 + lr;
            #pragma unroll
            for (int ks = 0; ks < 4; ++ks)
                uf[nt][ks] = *(const bf16x8*)(utlds + row * 128
                                              + (((ks * 4 + lg) ^ swz) << 3));
        }
        #pragma unroll
        for (int mt = 0; mt < 4; ++mt) {
            const int row = wm * 64 + mt * 16 + lr;
            bf16x8 lf[4];
            #pragma unroll
            for (int ks = 0; ks < 4; ++ks)
                lf[ks] = *(const bf16x8*)(llds + row * 128
                                          + (((ks * 4 + lg) ^ swz) << 3));
            #pragma unroll
            for (int ks = 0; ks < 4; ++ks)
                #pragma unroll
                for (int nt = 0; nt < 2; ++nt) {
                    if ((cc & 3) < 2)
                        yre[mt][nt] = MFMA16(lf[ks], uf[nt][ks], yre[mt][nt]);
                    else
                        yim[mt][nt] = MFMA16(lf[ks], uf[nt][ks], yim[mt][nt]);
                }
        }
        __syncthreads();   // protects utlds + llds before next c's writes
    }

    // ---- epilogue: interleave (re,im) -> coalesced float2 stores
    float2* o2 = (float2*)out;
    float2* obase = o2 + (size_t)(b * 1024 + p * 128 + wm * 64 + lg * 4) * 1024
                       + q * 128 + wn * 32 + lr;
    #pragma unroll
    for (int mt = 0; mt < 4; ++mt)
        #pragma unroll
        for (int nt = 0; nt < 2; ++nt)
            #pragma unroll
            for (int j = 0; j < 4; ++j) {
                float2 v;
                v.x = yre[mt][nt][j];
                v.y = yim[mt][nt][j];
                obase[(mt * 16 + j) * 1024 + nt * 16] = v;
            }
}

extern "C" void kernel_launch(void* const* d_in, const int* in_sizes, int n_in,
                              void* d_out, int out_size, void* d_ws, size_t ws_size,
                              hipStream_t stream) {
    const float* x  = (const float*)d_in[0];
    const int* perm = (const int*)d_in[1];
    unsigned short* htp = (unsigned short*)d_ws;   // 2 MB

    hipLaunchKernelGGL(prep_h, dim3(64), dim3(256), 0, stream,
        (const float*)d_in[2], (const float*)d_in[3], (const float*)d_in[4],
        (const float*)d_in[5], (const float*)d_in[6], (const float*)d_in[7],
        (const float*)d_in[8], (const float*)d_in[9], htp);
    hipLaunchKernelGGL(bilin_main, dim3(256), dim3(512), 0, stream,
        x, perm, htp, (float*)d_out);
}

// Round 6
// 47.959 us; speedup vs baseline: 1.5273x; 1.5273x over previous
//
#include <hip/hip_runtime.h>
#include <hip/hip_bf16.h>
#include <stdint.h>

typedef __attribute__((ext_vector_type(8))) short bf16x8;
typedef __attribute__((ext_vector_type(4))) float f32x4;
typedef __attribute__((ext_vector_type(16))) float f32x16;

#define MFMA32(a, b, c) __builtin_amdgcn_mfma_f32_32x32x16_bf16((a), (b), (c), 0, 0, 0)

__device__ __forceinline__ unsigned short f2bf_rn(float f) {
    union { __bf16 b; unsigned short u; } v;
    v.b = (__bf16)f;
    return v.u;
}

// pack 2 floats -> 2 bf16 in a uint (compiler fuses to v_cvt_pk_bf16_f32)
__device__ __forceinline__ unsigned int pk2(float lo, float hi) {
    union { unsigned short s[2]; unsigned int u; } r;
    r.s[0] = f2bf_rn(lo); r.s[1] = f2bf_rn(hi);
    return r.u;
}

__device__ __forceinline__ void gload_lds16(const void* g, void* l) {
    __builtin_amdgcn_global_load_lds(
        (const __attribute__((address_space(1))) void*)g,
        (__attribute__((address_space(3))) void*)l, 16, 0, 0);
}

// ---------------------------------------------------------------------------
// prep_h: transpose each 128x128 fp32 block of the 8 H tensors to bf16.
//   ht[j][blk][k][r] = h_j[blk][r][k]   (j = input order hr1,hi1,...,hi4)
// Lt_c = ht[c], Wt_c = ht[rperm[c]].
// ---------------------------------------------------------------------------
__global__ __launch_bounds__(256) void prep_h(
    const float* __restrict__ h0, const float* __restrict__ h1,
    const float* __restrict__ h2, const float* __restrict__ h3,
    const float* __restrict__ h4, const float* __restrict__ h5,
    const float* __restrict__ h6, const float* __restrict__ h7,
    unsigned short* __restrict__ ht)
{
    const float* hmap[8] = {h0, h1, h2, h3, h4, h5, h6, h7};
    const int wg = blockIdx.x;        // 64 = j(8) x blk(8)
    const float* src = hmap[wg >> 3] + (wg & 7) * 16384;
    unsigned short* dst = ht + wg * 16384;
    __shared__ unsigned short tile[128 * 129];
    const int t = threadIdx.x;
    #pragma unroll 4
    for (int i = 0; i < 64; ++i) {
        int idx = t + 256 * i, r = idx >> 7, k = idx & 127;
        tile[r * 129 + k] = f2bf_rn(src[idx]);
    }
    __syncthreads();
    #pragma unroll 4
    for (int i = 0; i < 64; ++i) {
        int idx = t + 256 * i, k = idx >> 7, r = idx & 127;
        dst[idx] = tile[r * 129 + k];
    }
}

// ---------------------------------------------------------------------------
// prep_x: x (B,16,64,16,64,2) fp32 -> permuted bf16 planes Xre/Xim (B,1024,1024)
// ---------------------------------------------------------------------------
__global__ __launch_bounds__(256) void prep_x(
    const float* __restrict__ x, const int* __restrict__ perm,
    unsigned short* __restrict__ xre, unsigned short* __restrict__ xim)
{
    const int id = blockIdx.x * 256 + threadIdx.x;   // 4*1024*256 total
    const int b = id >> 18;
    const int row = (id >> 8) & 1023;
    const int col0 = (id & 255) * 4;
    const int n1 = perm[row >> 6], r1 = row & 63;
    const int n2 = perm[col0 >> 6], r2 = col0 & 63;
    const int src = (((b * 16 + n1) * 64 + r1) * 16 + n2) * 64 + r2;  // float2 units
    const float4* s = (const float4*)(x + src * 2);
    float4 v0 = s[0], v1 = s[1];
    ushort4 re, im;
    re.x = f2bf_rn(v0.x); re.y = f2bf_rn(v0.z); re.z = f2bf_rn(v1.x); re.w = f2bf_rn(v1.z);
    im.x = f2bf_rn(v0.y); im.y = f2bf_rn(v0.w); im.z = f2bf_rn(v1.y); im.w = f2bf_rn(v1.w);
    const int o = id * 4;
    *(ushort4*)(xre + o) = re;
    *(ushort4*)(xim + o) = im;
}

// ---------------------------------------------------------------------------
// bilin_main: 256 WGs = (b,p,q), q = bid&7 (XCD-locked). 512 threads = 8
// waves: wn = wid&3 (32-col group), h = wid>>2 (64-row half, split-K pair).
// 32x32x16 MFMA. Per c-term:
//   stage A: U[64x32] = X[h-rows] . W_c[:,wn-cols]  (xf/wf from swizzled LDS)
//   in-reg wave-local transpose via cvt-pack + __shfl_xor(32) (no barrier)
//   stage B: Ypart[128x32] += Lt_c[., h-rows] . U   (lf from LDS)
// 2 __syncthreads per c; every gload_lds batch drains >=1 compute stage
// after issue. Epilogue sums the h=0/h=1 partials through reused LDS.
// LDS swizzle: 16B chunk ch of row at LDS[row][ch] = G[row][ch ^ (row&15)].
// ---------------------------------------------------------------------------
__global__ __launch_bounds__(512, 2) void bilin_main(
    const unsigned short* __restrict__ xre,
    const unsigned short* __restrict__ xim,
    const unsigned short* __restrict__ ht,
    float* __restrict__ out)
{
    const int wg = blockIdx.x;
    const int q = wg & 7, p = (wg >> 3) & 7, b = wg >> 6;
    const int tid = threadIdx.x;
    const int lane = tid & 63, wid = tid >> 6;
    const int wn = wid & 3, h = wid >> 2;
    const int l31 = lane & 31, hl = lane >> 5;

    __shared__ __align__(16) unsigned short smem[65536];   // 128 KB
    unsigned short* xlds  = smem;            // 32 KB
    unsigned short* wldsA = smem + 16384;    // 32 KB
    unsigned short* wldsB = smem + 32768;    // 32 KB
    unsigned short* llds  = smem + 49152;    // 32 KB

    constexpr int cseq[8]  = {0, 1, 6, 7, 2, 3, 4, 5};
    constexpr int rperm[8] = {0, 1, 3, 2, 4, 5, 7, 6};

    f32x16 yre[4], yim[4];
    #pragma unroll
    for (int i = 0; i < 4; ++i) {
        #pragma unroll
        for (int e = 0; e < 16; ++e) { yre[i][e] = 0.f; yim[i][e] = 0.f; }
    }

    // ---- staging helpers (gload_lds: wave-uniform LDS base + lane*16) ----
    const int wubase = tid & ~63;
    auto stage_h = [&](unsigned short* dst, int blk) {
        const unsigned short* src = ht + blk * 16384;
        #pragma unroll
        for (int r = 0; r < 4; ++r) {
            const int idx = r * 512 + tid;          // 16B chunk 0..2047
            const int row = idx >> 4, cin = idx & 15;
            gload_lds16(src + row * 128 + ((cin ^ (row & 15)) << 3),
                        dst + ((r * 512 + wubase) << 3));
        }
    };
    auto stage_x = [&](const unsigned short* xp) {
        const unsigned short* src = xp + (size_t)(b * 1024 + p * 128) * 1024 + q * 128;
        #pragma unroll
        for (int r = 0; r < 4; ++r) {
            const int idx = r * 512 + tid;
            const int row = idx >> 4, cin = idx & 15;
            gload_lds16(src + row * 1024 + ((cin ^ (row & 15)) << 3),
                        xlds + ((r * 512 + wubase) << 3));
        }
    };

    // swizzled LDS fragment read: row in [0,128), chunk in [0,16)
    auto ldr = [&](const unsigned short* base, int row, int ch) -> bf16x8 {
        return *(const bf16x8*)(base + row * 128 + ((ch ^ (row & 15)) << 3));
    };

    // ---- prologue: stage W(c0), Lt(c0), X(g0) ----
    stage_h(wldsA, rperm[0] * 8 + q);
    stage_h(llds, 0 * 8 + p);
    stage_x(xre);
    __syncthreads();

    #pragma unroll
    for (int cc = 0; cc < 8; ++cc) {
        const int c = cseq[cc];
        const unsigned short* wb = (cc & 1) ? wldsB : wldsA;
        unsigned short* wbn = (cc & 1) ? wldsA : wldsB;

        // ---- stage A: u[m2] (32x32 C-frags), rows h*64+m2*32, cols wn*32
        f32x16 u[2];
        #pragma unroll
        for (int e = 0; e < 16; ++e) { u[0][e] = 0.f; u[1][e] = 0.f; }
        #pragma unroll
        for (int ks = 0; ks < 8; ++ks) {
            bf16x8 wfr = ldr(wb, wn * 32 + l31, 2 * ks + hl);
            #pragma unroll
            for (int m2 = 0; m2 < 2; ++m2) {
                bf16x8 xfr = ldr(xlds, h * 64 + m2 * 32 + l31, 2 * ks + hl);
                u[m2] = MFMA32(xfr, wfr, u[m2]);
            }
        }

        __syncthreads();   // MID: drains Lt_c (issued end of cc-1) -> stage B safe
        if (cc < 7) stage_h(wbn, rperm[cseq[cc + 1]] * 8 + q);  // drain @ END
        if (cc == 3) stage_x(xim);                              // drain @ END

        // ---- stage B: Ypart += Lt_c . U  (K = this wave's 64 rows)
        #pragma unroll
        for (int t = 0; t < 4; ++t) {
            // B-frag for k-step t from C-frags u[t>>1]: element j (lane hl,l31)
            // must equal U[16*t + 8*hl + j][l31].  Pack pairs then exchange
            // halves with shfl_xor(32):
            //   hl=0 keeps its rows {0..3}, takes partner's {4..7}
            //   hl=1 takes partner's {8..11}, keeps its {12..15}
            const int f = t >> 1, qa = (t & 1) * 2, qb = qa + 1;
            unsigned int lo0 = pk2(u[f][4 * qa + 0], u[f][4 * qa + 1]);
            unsigned int lo1 = pk2(u[f][4 * qa + 2], u[f][4 * qa + 3]);
            unsigned int hi0 = pk2(u[f][4 * qb + 0], u[f][4 * qb + 1]);
            unsigned int hi1 = pk2(u[f][4 * qb + 2], u[f][4 * qb + 3]);
            unsigned int sxl0 = (unsigned int)__shfl_xor((int)lo0, 32);
            unsigned int sxl1 = (unsigned int)__shfl_xor((int)lo1, 32);
            unsigned int sxh0 = (unsigned int)__shfl_xor((int)hi0, 32);
            unsigned int sxh1 = (unsigned int)__shfl_xor((int)hi1, 32);
            union { unsigned int d[4]; bf16x8 v; } ufu;
            ufu.d[0] = hl ? sxh0 : lo0;
            ufu.d[1] = hl ? sxh1 : lo1;
            ufu.d[2] = hl ? hi0 : sxl0;
            ufu.d[3] = hl ? hi1 : sxl1;
            #pragma unroll
            for (int mt = 0; mt < 4; ++mt) {
                bf16x8 lfr = ldr(llds, mt * 32 + l31, 8 * h + 2 * t + hl);
                if ((cc & 3) < 2) yre[mt] = MFMA32(lfr, ufu.v, yre[mt]);
                else              yim[mt] = MFMA32(lfr, ufu.v, yim[mt]);
            }
        }

        __syncthreads();   // END: all done reading llds; drains W/X stages
        if (cc < 7) stage_h(llds, cseq[cc + 1] * 8 + p);        // drain @ next MID
    }

    // ---- epilogue: sum split-K partials (h=1 dumps, h=0 adds + stores) ----
    float* red = (float*)smem + wn * 8192;   // 32 KB per wn group
    if (h == 1) {
        #pragma unroll
        for (int mt = 0; mt < 4; ++mt)
            #pragma unroll
            for (int q4 = 0; q4 < 4; ++q4) {
                f32x4 vr, vi;
                #pragma unroll
                for (int jj = 0; jj < 4; ++jj) {
                    vr[jj] = yre[mt][4 * q4 + jj];
                    vi[jj] = yim[mt][4 * q4 + jj];
                }
                *(f32x4*)(red + ((0 * 4 + mt) * 4 + q4) * 256 + lane * 4) = vr;
                *(f32x4*)(red + ((1 * 4 + mt) * 4 + q4) * 256 + lane * 4) = vi;
            }
    }
    __syncthreads();
    if (h == 0) {
        float2* o2 = (float2*)out;
        #pragma unroll
        for (int mt = 0; mt < 4; ++mt)
            #pragma unroll
            for (int q4 = 0; q4 < 4; ++q4) {
                f32x4 pr = *(const f32x4*)(red + ((0 * 4 + mt) * 4 + q4) * 256 + lane * 4);
                f32x4 pi = *(const f32x4*)(red + ((1 * 4 + mt) * 4 + q4) * 256 + lane * 4);
                #pragma unroll
                for (int jj = 0; jj < 4; ++jj) {
                    const int j = 4 * q4 + jj;
                    const int row = mt * 32 + (j & 3) + 8 * (j >> 2) + 4 * hl;
                    float2 v;
                    v.x = yre[mt][j] + pr[jj];
                    v.y = yim[mt][j] + pi[jj];
                    o2[(size_t)(b * 1024 + p * 128 + row) * 1024
                       + q * 128 + wn * 32 + l31] = v;
                }
            }
    }
}

extern "C" void kernel_launch(void* const* d_in, const int* in_sizes, int n_in,
                              void* d_out, int out_size, void* d_ws, size_t ws_size,
                              hipStream_t stream) {
    const float* x  = (const float*)d_in[0];
    const int* perm = (const int*)d_in[1];
    unsigned short* ws = (unsigned short*)d_ws;
    // workspace (ushort units): Ht 1M | Xre 4M | Xim 4M = 18 MB
    unsigned short* htp = ws;
    unsigned short* xre = ws + 1u * 1024u * 1024u;
    unsigned short* xim = ws + 5u * 1024u * 1024u;

    hipLaunchKernelGGL(prep_h, dim3(64), dim3(256), 0, stream,
        (const float*)d_in[2], (const float*)d_in[3], (const float*)d_in[4],
        (const float*)d_in[5], (const float*)d_in[6], (const float*)d_in[7],
        (const float*)d_in[8], (const float*)d_in[9], htp);
    hipLaunchKernelGGL(prep_x, dim3(4096), dim3(256), 0, stream,
        x, perm, xre, xim);
    hipLaunchKernelGGL(bilin_main, dim3(256), dim3(512), 0, stream,
        xre, xim, htp, (float*)d_out);
}